// Round 6
// baseline (432.482 us; speedup 1.0000x reference)
//
#include <hip/hip_runtime.h>
#include <math.h>

#define N_NODES 50000
#define N_EDGES 800000
#define D_IN 256
#define D_HID 128
#define ALPHA 0.1f
#define EPS 1e-5f

#define NBUCK 391   // ceil(50000/128)
#define EPB 4096    // edges per histogram/scatter block
#define NBLK 196    // ceil(800000/4096)

typedef __attribute__((ext_vector_type(8))) short bf16x8;
typedef __attribute__((ext_vector_type(4))) float f32x4;

static __device__ __forceinline__ unsigned short f2bf(float f) {
    unsigned int x = __float_as_uint(f);
    return (unsigned short)((x + 0x7fffu + ((x >> 16) & 1u)) >> 16);
}
static __device__ __forceinline__ float blo(unsigned int v) {
    return __uint_as_float(v << 16);
}
static __device__ __forceinline__ float bhi(unsigned int v) {
    return __uint_as_float(v & 0xffff0000u);
}
static __device__ __forceinline__ void unpack8(uint4 u, float* f) {
    f[0] = blo(u.x); f[1] = bhi(u.x);
    f[2] = blo(u.y); f[3] = bhi(u.y);
    f[4] = blo(u.z); f[5] = bhi(u.z);
    f[6] = blo(u.w); f[7] = bhi(u.w);
}

// ---------------- CSR build: hierarchical counting sort ----------------
__global__ __launch_bounds__(256) void k_hist(const int* __restrict__ dst,
                                              int* __restrict__ hist, int e) {
    __shared__ int h[NBUCK];
    int t = threadIdx.x;
    for (int i = t; i < NBUCK; i += 256) h[i] = 0;
    __syncthreads();
    int base = blockIdx.x * EPB;
    int lim = e - base;
    if (lim > EPB) lim = EPB;
    for (int i = t; i < lim; i += 256) atomicAdd(&h[dst[base + i] >> 7], 1);
    __syncthreads();
    for (int i = t; i < NBUCK; i += 256) hist[blockIdx.x * NBUCK + i] = h[i];
}

__global__ __launch_bounds__(256) void k_bkscan(const int* __restrict__ hist,
                                                int* __restrict__ offsT, int* __restrict__ btot) {
    __shared__ int sh[256];
    int b = blockIdx.x;
    int t = threadIdx.x;
    int v = (t < NBLK) ? hist[t * NBUCK + b] : 0;
    sh[t] = v;
    __syncthreads();
    for (int ofs = 1; ofs < 256; ofs <<= 1) {
        int y = (t >= ofs) ? sh[t - ofs] : 0;
        __syncthreads();
        sh[t] += y;
        __syncthreads();
    }
    if (t < NBLK) offsT[b * NBLK + t] = sh[t] - v;
    if (t == 255) btot[b] = sh[255];
}

__global__ __launch_bounds__(512) void k_bbase(const int* __restrict__ btot,
                                               int* __restrict__ bbase, int* __restrict__ rp) {
    __shared__ int sh[512];
    int t = threadIdx.x;
    int v = (t < NBUCK) ? btot[t] : 0;
    sh[t] = v;
    __syncthreads();
    for (int ofs = 1; ofs < 512; ofs <<= 1) {
        int y = (t >= ofs) ? sh[t - ofs] : 0;
        __syncthreads();
        sh[t] += y;
        __syncthreads();
    }
    if (t < NBUCK) bbase[t] = sh[t] - v;
    if (t == 0) rp[N_NODES] = N_EDGES;
}

__global__ __launch_bounds__(256) void k_scatter(const int* __restrict__ src,
                                                 const int* __restrict__ dst,
                                                 const int* __restrict__ offsT,
                                                 const int* __restrict__ bbase,
                                                 unsigned int* __restrict__ buck, int e) {
    __shared__ int h[NBUCK];
    int t = threadIdx.x;
    for (int i = t; i < NBUCK; i += 256) h[i] = 0;
    __syncthreads();
    int base = blockIdx.x * EPB;
    int lim = e - base;
    if (lim > EPB) lim = EPB;
    for (int i = t; i < lim; i += 256) {
        int d = dst[base + i];
        int s = src[base + i];
        int b = d >> 7;
        int lp = atomicAdd(&h[b], 1);
        int pos = bbase[b] + offsT[b * NBLK + blockIdx.x] + lp;
        buck[pos] = (unsigned int)s | ((unsigned int)(d & 127) << 16);
    }
}

__global__ __launch_bounds__(256) void k_csr(const unsigned int* __restrict__ buck,
                                             const int* __restrict__ bbase,
                                             const int* __restrict__ btot,
                                             int* __restrict__ rp, float* __restrict__ dinv,
                                             int* __restrict__ cs) {
    __shared__ int dcnt[128];
    __shared__ int doff[128];
    int b = blockIdx.x;
    int t = threadIdx.x;
    if (t < 128) dcnt[t] = 0;
    __syncthreads();
    int base = bbase[b];
    int tot = btot[b];
    for (int i = t; i < tot; i += 256) {
        unsigned int v = buck[base + i];
        atomicAdd(&dcnt[(v >> 16) & 127], 1);
    }
    __syncthreads();
    if (t < 128) doff[t] = dcnt[t];
    __syncthreads();
    for (int ofs = 1; ofs < 128; ofs <<= 1) {
        int y = 0;
        if (t < 128 && t >= ofs) y = doff[t - ofs];
        __syncthreads();
        if (t < 128) doff[t] += y;
        __syncthreads();
    }
    int gd0 = b << 7;
    if (t < 128) {
        int ex = doff[t] - dcnt[t];
        if (gd0 + t < N_NODES) {
            rp[gd0 + t] = base + ex;
            dinv[gd0 + t] = rsqrtf((float)(dcnt[t] + 1));
        }
        dcnt[t] = ex;
    }
    __syncthreads();
    for (int i = t; i < tot; i += 256) {
        unsigned int v = buck[base + i];
        int p = atomicAdd(&dcnt[(v >> 16) & 127], 1);
        cs[base + p] = (int)(v & 0xffffu);
    }
}

// ---------------- prep weights ----------------
__global__ __launch_bounds__(256) void k_prep_w(const float* __restrict__ W_lin,
                                                const float* __restrict__ W1s,
                                                unsigned short* __restrict__ Wlt,
                                                unsigned short* __restrict__ Wt) {
    int idx = blockIdx.x * 256 + threadIdx.x;
    if (idx < 128 * 256) {
        int c = idx >> 8, k = idx & 255;
        Wlt[idx] = f2bf(W_lin[k * 128 + c]);
    } else {
        int j = idx - 128 * 256;
        if (j < 5 * 128 * 128) {
            int l = j >> 14;
            int rem = j & 16383;
            int c = rem >> 7, k = rem & 127;
            float bet = logf(0.5f / (float)(l + 1) + 1.0f);
            float v = bet * W1s[l * 16384 + k * 128 + c];
            if (c == k) v += 1.0f - bet;
            Wt[j] = f2bf(v);
        }
    }
}

// ---------------- first GEMM (K=256, f32 A input, cast fused): out bf16 ----------------
template <int K>
__global__ __launch_bounds__(256) void k_mgemm(const float* __restrict__ A,
                                               const unsigned short* __restrict__ Bt,
                                               unsigned short* __restrict__ outb, int M) {
    __shared__ short lds[2 * 128 * 136];
    short* As = lds;
    short* Bs = lds + 128 * 136;

    int t = threadIdx.x;
    int lane = t & 63;
    int wave = t >> 6;
    int wr = wave >> 1, wc = wave & 1;
    int row0 = blockIdx.x * 128;

    f32x4 acc[4][4];
#pragma unroll
    for (int m = 0; m < 4; ++m)
#pragma unroll
        for (int n = 0; n < 4; ++n) acc[m][n] = (f32x4){0.f, 0.f, 0.f, 0.f};

    int sr = t >> 1;
    int sh = t & 1;

    for (int k0 = 0; k0 < K; k0 += 128) {
        {
            int gr = row0 + sr;
            float4 zf = {0.f, 0.f, 0.f, 0.f};
            const float4* gp = (const float4*)(A + (size_t)gr * K + k0 + sh * 64);
#pragma unroll
            for (int u = 0; u < 8; ++u) {
                float4 a = (gr < M) ? gp[2 * u] : zf;
                float4 b = (gr < M) ? gp[2 * u + 1] : zf;
                uint4 w;
                w.x = (unsigned int)f2bf(a.x) | ((unsigned int)f2bf(a.y) << 16);
                w.y = (unsigned int)f2bf(a.z) | ((unsigned int)f2bf(a.w) << 16);
                w.z = (unsigned int)f2bf(b.x) | ((unsigned int)f2bf(b.y) << 16);
                w.w = (unsigned int)f2bf(b.z) | ((unsigned int)f2bf(b.w) << 16);
                *(uint4*)(As + sr * 136 + sh * 64 + u * 8) = w;
            }
        }
        {
            const uint4* gp = (const uint4*)(Bt + (size_t)sr * K + k0 + sh * 64);
#pragma unroll
            for (int u = 0; u < 8; ++u) {
                *(uint4*)(Bs + sr * 136 + sh * 64 + u * 8) = gp[u];
            }
        }
        __syncthreads();

#pragma unroll
        for (int ks = 0; ks < 4; ++ks) {
            bf16x8 af[4], bfr[4];
#pragma unroll
            for (int m = 0; m < 4; ++m)
                af[m] = *(const bf16x8*)(As + (wr * 64 + m * 16 + (lane & 15)) * 136 + ks * 32 + (lane >> 4) * 8);
#pragma unroll
            for (int n = 0; n < 4; ++n)
                bfr[n] = *(const bf16x8*)(Bs + (wc * 64 + n * 16 + (lane & 15)) * 136 + ks * 32 + (lane >> 4) * 8);
#pragma unroll
            for (int m = 0; m < 4; ++m)
#pragma unroll
                for (int n = 0; n < 4; ++n)
                    acc[m][n] = __builtin_amdgcn_mfma_f32_16x16x32_bf16(af[m], bfr[n], acc[m][n], 0, 0, 0);
        }
        __syncthreads();
    }

    short* Z = lds;
#pragma unroll
    for (int m = 0; m < 4; ++m)
#pragma unroll
        for (int n = 0; n < 4; ++n)
#pragma unroll
            for (int r = 0; r < 4; ++r) {
                int rl = wr * 64 + m * 16 + (lane >> 4) * 4 + r;
                int cl = wc * 64 + n * 16 + (lane & 15);
                Z[rl * 136 + cl] = (short)f2bf(acc[m][n][r]);
            }
    __syncthreads();
    int gr = row0 + sr;
    if (gr < M) {
#pragma unroll
        for (int u = 0; u < 8; ++u)
            *(uint4*)(outb + (size_t)gr * 128 + sh * 64 + u * 8) = *(uint4*)(Z + sr * 136 + sh * 64 + u * 8);
    }
}

// ---------------- layer GEMM (K=128): B in registers ----------------
template <int MODE>
__global__ __launch_bounds__(256) void k_lgemm(const unsigned short* __restrict__ A,
                                               const unsigned short* __restrict__ Bt,
                                               unsigned short* __restrict__ outb,
                                               float* __restrict__ outf,
                                               float* __restrict__ bn_s, float* __restrict__ bn_q,
                                               int M) {
    __shared__ short As[128 * 136];
    int t = threadIdx.x;
    int lane = t & 63;
    int wave = t >> 6;
    int wr = wave >> 1, wc = wave & 1;
    int row0 = blockIdx.x * 128;

    bf16x8 bfr[4][4];
#pragma unroll
    for (int ks = 0; ks < 4; ++ks)
#pragma unroll
        for (int n = 0; n < 4; ++n)
            bfr[ks][n] = *(const bf16x8*)(Bt + (size_t)(wc * 64 + n * 16 + (lane & 15)) * 128 + ks * 32 + (lane >> 4) * 8);

    int sr = t >> 1, sh = t & 1;
    {
        int gr = row0 + sr;
        uint4 zero = {0, 0, 0, 0};
        const uint4* gp = (const uint4*)(A + (size_t)gr * 128 + sh * 64);
#pragma unroll
        for (int u = 0; u < 8; ++u) {
            uint4 v = (gr < M) ? gp[u] : zero;
            *(uint4*)(As + sr * 136 + sh * 64 + u * 8) = v;
        }
    }
    __syncthreads();

    f32x4 acc[4][4];
#pragma unroll
    for (int m = 0; m < 4; ++m)
#pragma unroll
        for (int n = 0; n < 4; ++n) acc[m][n] = (f32x4){0.f, 0.f, 0.f, 0.f};

#pragma unroll
    for (int ks = 0; ks < 4; ++ks) {
        bf16x8 af[4];
#pragma unroll
        for (int m = 0; m < 4; ++m)
            af[m] = *(const bf16x8*)(As + (wr * 64 + m * 16 + (lane & 15)) * 136 + ks * 32 + (lane >> 4) * 8);
#pragma unroll
        for (int m = 0; m < 4; ++m)
#pragma unroll
            for (int n = 0; n < 4; ++n)
                acc[m][n] = __builtin_amdgcn_mfma_f32_16x16x32_bf16(af[m], bfr[ks][n], acc[m][n], 0, 0, 0);
    }

    if (MODE == 1) {
        float sum[4] = {0.f, 0.f, 0.f, 0.f}, sq[4] = {0.f, 0.f, 0.f, 0.f};
#pragma unroll
        for (int n = 0; n < 4; ++n)
#pragma unroll
            for (int m = 0; m < 4; ++m)
#pragma unroll
                for (int r = 0; r < 4; ++r) {
                    float v = acc[m][n][r];
                    sum[n] += v;
                    sq[n] += v * v;
                }
#pragma unroll
        for (int n = 0; n < 4; ++n) {
            sum[n] += __shfl_xor(sum[n], 16);
            sum[n] += __shfl_xor(sum[n], 32);
            sq[n] += __shfl_xor(sq[n], 16);
            sq[n] += __shfl_xor(sq[n], 32);
        }
        if (lane < 16) {
#pragma unroll
            for (int n = 0; n < 4; ++n) {
                int col = wc * 64 + n * 16 + lane;
                atomicAdd(&bn_s[col], sum[n]);
                atomicAdd(&bn_q[col], sq[n]);
            }
        }
    }

    if (MODE == 2) {
#pragma unroll
        for (int m = 0; m < 4; ++m)
#pragma unroll
            for (int n = 0; n < 4; ++n)
#pragma unroll
                for (int r = 0; r < 4; ++r) {
                    int gr = row0 + wr * 64 + m * 16 + (lane >> 4) * 4 + r;
                    int cl = wc * 64 + n * 16 + (lane & 15);
                    if (gr < M) outf[(size_t)gr * 128 + cl] = acc[m][n][r];
                }
    } else {
        __syncthreads();
        short* Z = As;
#pragma unroll
        for (int m = 0; m < 4; ++m)
#pragma unroll
            for (int n = 0; n < 4; ++n)
#pragma unroll
                for (int r = 0; r < 4; ++r) {
                    int rl = wr * 64 + m * 16 + (lane >> 4) * 4 + r;
                    int cl = wc * 64 + n * 16 + (lane & 15);
                    Z[rl * 136 + cl] = (short)f2bf(acc[m][n][r]);
                }
        __syncthreads();
        int gr = row0 + sr;
        if (gr < M) {
#pragma unroll
            for (int u = 0; u < 8; ++u)
                *(uint4*)(outb + (size_t)gr * 128 + sh * 64 + u * 8) = *(uint4*)(Z + sr * 136 + sh * 64 + u * 8);
        }
    }
}

// ---------------- aggregation: one wave per node, 4 rows per dwordx4 gather ----------------
// lane = 16*q + c : quarter q handles row j+q, col-slice c (8 bf16 = 16 B).
// MODE 0: GCNConv; MODE 1: GCN2 plain; MODE 2: GCN2 + fused BN/ReLU
template <int MODE>
__global__ __launch_bounds__(256) void k_agg(const uint4* __restrict__ src4,
                                             const uint4* __restrict__ x04,
                                             const int* __restrict__ rp, const int* __restrict__ cs,
                                             const float* __restrict__ dinv,
                                             const float* __restrict__ b_lin,
                                             const float* __restrict__ st,
                                             uint4* __restrict__ dst4,
                                             float* __restrict__ bns, int n) {
    if (blockIdx.x == 0) bns[threadIdx.x] = 0.f;  // zero BN stats for the following GEMM

    int wid = (blockIdx.x * 256 + threadIdx.x) >> 6;
    int lane = threadIdx.x & 63;
    if (wid >= n) return;
    int q = lane >> 4;
    int c = lane & 15;

    int start = __builtin_amdgcn_readfirstlane(rp[wid]);
    int end = __builtin_amdgcn_readfirstlane(rp[wid + 1]);

    float sc[8], tc[8];
    if (MODE == 2) {
        float4 s0 = ((const float4*)st)[c * 2];
        float4 s1 = ((const float4*)st)[c * 2 + 1];
        float4 t0 = ((const float4*)st)[32 + c * 2];
        float4 t1 = ((const float4*)st)[32 + c * 2 + 1];
        sc[0] = s0.x; sc[1] = s0.y; sc[2] = s0.z; sc[3] = s0.w;
        sc[4] = s1.x; sc[5] = s1.y; sc[6] = s1.z; sc[7] = s1.w;
        tc[0] = t0.x; tc[1] = t0.y; tc[2] = t0.z; tc[3] = t0.w;
        tc[4] = t1.x; tc[5] = t1.y; tc[6] = t1.z; tc[7] = t1.w;
    }
    float dn = (MODE == 0) ? dinv[wid] : 0.f;

    float acc[8];
#pragma unroll
    for (int i = 0; i < 8; ++i) acc[i] = 0.f;

#define ACCUM(vv, ww)                                                     \
    {                                                                     \
        float f_[8];                                                      \
        unpack8(vv, f_);                                                  \
        if (MODE == 0) {                                                  \
            _Pragma("unroll") for (int i_ = 0; i_ < 8; ++i_)              \
                acc[i_] = fmaf(ww, f_[i_], acc[i_]);                      \
        } else if (MODE == 1) {                                           \
            _Pragma("unroll") for (int i_ = 0; i_ < 8; ++i_)              \
                acc[i_] += f_[i_];                                        \
        } else {                                                          \
            _Pragma("unroll") for (int i_ = 0; i_ < 8; ++i_)              \
                acc[i_] += fmaxf(fmaf(sc[i_], f_[i_], tc[i_]), 0.f);      \
        }                                                                 \
    }

    for (int base = start; base < end; base += 64) {
        int cnt = end - base;
        if (cnt > 64) cnt = 64;
        int myi = cs[base + ((lane < cnt) ? lane : 0)];
        float myw = (MODE == 0) ? dinv[myi] : 0.f;

        int j = 0;
        for (; j + 15 < cnt; j += 16) {
            int s0 = __shfl(myi, j + q);
            int s1 = __shfl(myi, j + 4 + q);
            int s2 = __shfl(myi, j + 8 + q);
            int s3 = __shfl(myi, j + 12 + q);
            uint4 v0 = src4[(size_t)s0 * 16 + c];
            uint4 v1 = src4[(size_t)s1 * 16 + c];
            uint4 v2 = src4[(size_t)s2 * 16 + c];
            uint4 v3 = src4[(size_t)s3 * 16 + c];
            float w0 = 0.f, w1 = 0.f, w2 = 0.f, w3 = 0.f;
            if (MODE == 0) {
                w0 = __shfl(myw, j + q) * dn;
                w1 = __shfl(myw, j + 4 + q) * dn;
                w2 = __shfl(myw, j + 8 + q) * dn;
                w3 = __shfl(myw, j + 12 + q) * dn;
            }
            ACCUM(v0, w0);
            ACCUM(v1, w1);
            ACCUM(v2, w2);
            ACCUM(v3, w3);
        }
        for (; j + 7 < cnt; j += 8) {
            int s0 = __shfl(myi, j + q);
            int s1 = __shfl(myi, j + 4 + q);
            uint4 v0 = src4[(size_t)s0 * 16 + c];
            uint4 v1 = src4[(size_t)s1 * 16 + c];
            float w0 = 0.f, w1 = 0.f;
            if (MODE == 0) {
                w0 = __shfl(myw, j + q) * dn;
                w1 = __shfl(myw, j + 4 + q) * dn;
            }
            ACCUM(v0, w0);
            ACCUM(v1, w1);
        }
        for (; j + 3 < cnt; j += 4) {
            int s0 = __shfl(myi, j + q);
            uint4 v0 = src4[(size_t)s0 * 16 + c];
            float w0 = 0.f;
            if (MODE == 0) w0 = __shfl(myw, j + q) * dn;
            ACCUM(v0, w0);
        }
        int rem = cnt - j;
        if (rem > 0) {
            int jj = j + q;
            bool act = jj < cnt;
            int jsafe = act ? jj : (cnt - 1);
            int s0 = __shfl(myi, jsafe);
            uint4 v0 = src4[(size_t)s0 * 16 + c];
            float m = act ? 1.f : 0.f;
            if (MODE == 0) {
                float w0 = __shfl(myw, jsafe) * dn * m;
                ACCUM(v0, w0);
            } else {
                float f_[8];
                unpack8(v0, f_);
                if (MODE == 1) {
#pragma unroll
                    for (int i_ = 0; i_ < 8; ++i_) acc[i_] = fmaf(m, f_[i_], acc[i_]);
                } else {
#pragma unroll
                    for (int i_ = 0; i_ < 8; ++i_)
                        acc[i_] = fmaf(m, fmaxf(fmaf(sc[i_], f_[i_], tc[i_]), 0.f), acc[i_]);
                }
            }
        }
    }
#undef ACCUM

    // fold quarters
#pragma unroll
    for (int i = 0; i < 8; ++i) {
        acc[i] += __shfl_xor(acc[i], 16);
        acc[i] += __shfl_xor(acc[i], 32);
    }

    if (MODE == 0) {
        uint4 sv = src4[(size_t)wid * 16 + c];
        float fs[8];
        unpack8(sv, fs);
        float w2 = dn * dn;
        float4 b0 = ((const float4*)b_lin)[c * 2];
        float4 b1 = ((const float4*)b_lin)[c * 2 + 1];
        float bb[8] = {b0.x, b0.y, b0.z, b0.w, b1.x, b1.y, b1.z, b1.w};
#pragma unroll
        for (int i = 0; i < 8; ++i) acc[i] = fmaf(w2, fs[i], acc[i]) + bb[i];
    } else {
        uint4 xv = x04[(size_t)wid * 16 + c];
        float fx[8];
        unpack8(xv, fx);
#pragma unroll
        for (int i = 0; i < 8; ++i) acc[i] = fmaf(ALPHA, fx[i], (1.0f - ALPHA) * acc[i]);
    }

    if (lane < 16) {
        uint4 o;
        o.x = (unsigned int)f2bf(acc[0]) | ((unsigned int)f2bf(acc[1]) << 16);
        o.y = (unsigned int)f2bf(acc[2]) | ((unsigned int)f2bf(acc[3]) << 16);
        o.z = (unsigned int)f2bf(acc[4]) | ((unsigned int)f2bf(acc[5]) << 16);
        o.w = (unsigned int)f2bf(acc[6]) | ((unsigned int)f2bf(acc[7]) << 16);
        dst4[(size_t)wid * 16 + c] = o;
    }
}

// ---------------- BN finalize ----------------
__global__ void k_bn_fin(const float* __restrict__ bn_s, const float* __restrict__ bn_q,
                         const float* __restrict__ gamma, const float* __restrict__ betap,
                         float* __restrict__ st, int n) {
    int c = threadIdx.x;
    float inv_n = 1.0f / (float)n;
    float mu = bn_s[c] * inv_n;
    float var = bn_q[c] * inv_n - mu * mu;
    var = fmaxf(var, 0.f);
    float s = gamma[c] * rsqrtf(var + EPS);
    st[c] = s;
    st[128 + c] = betap[c] - mu * s;
}

extern "C" void kernel_launch(void* const* d_in, const int* in_sizes, int n_in,
                              void* d_out, int out_size, void* d_ws, size_t ws_size,
                              hipStream_t stream) {
    const float* x = (const float*)d_in[0];
    const int* ei = (const int*)d_in[1];
    const float* W_lin = (const float*)d_in[2];
    const float* b_lin = (const float*)d_in[3];
    const float* W1s = (const float*)d_in[4];
    const float* gam = (const float*)d_in[5];
    const float* betp = (const float*)d_in[6];
    float* out = (float*)d_out;

    char* ws = (char*)d_ws;
    size_t off = 0;
    auto alloc = [&](size_t b) { size_t p = off; off = (off + b + 255) & ~(size_t)255; return p; };
    int* rp = (int*)(ws + alloc((size_t)(N_NODES + 1) * 4));
    int* cs = (int*)(ws + alloc((size_t)N_EDGES * 4));
    float* dinv = (float*)(ws + alloc((size_t)N_NODES * 4));
    int* hist = (int*)(ws + alloc((size_t)NBLK * NBUCK * 4));
    int* offsT = (int*)(ws + alloc((size_t)NBUCK * NBLK * 4));
    int* btot = (int*)(ws + alloc((size_t)NBUCK * 4));
    int* bbase = (int*)(ws + alloc((size_t)NBUCK * 4));
    unsigned int* buck = (unsigned int*)(ws + alloc((size_t)N_EDGES * 4));
    unsigned short* xwb = (unsigned short*)(ws + alloc((size_t)N_NODES * D_HID * 2));
    unsigned short* x0b = (unsigned short*)(ws + alloc((size_t)N_NODES * D_HID * 2));
    unsigned short* zb = (unsigned short*)(ws + alloc((size_t)N_NODES * D_HID * 2));
    unsigned short* hb = (unsigned short*)(ws + alloc((size_t)N_NODES * D_HID * 2));
    unsigned short* Wlt = (unsigned short*)(ws + alloc((size_t)128 * 256 * 2));
    unsigned short* Wt = (unsigned short*)(ws + alloc((size_t)5 * 128 * 128 * 2));
    float* bns = (float*)(ws + alloc(256 * 4));
    float* st = (float*)(ws + alloc(256 * 4));

    const int ggrid = (N_NODES + 127) / 128;
    const int agrid = (N_NODES + 3) / 4;

    // CSR build (counting sort, coalesced writes)
    k_hist<<<NBLK, 256, 0, stream>>>(ei + N_EDGES, hist, N_EDGES);
    k_bkscan<<<NBUCK, 256, 0, stream>>>(hist, offsT, btot);
    k_bbase<<<1, 512, 0, stream>>>(btot, bbase, rp);
    k_scatter<<<NBLK, 256, 0, stream>>>(ei, ei + N_EDGES, offsT, bbase, buck, N_EDGES);
    k_csr<<<NBUCK, 256, 0, stream>>>(buck, bbase, btot, rp, dinv, cs);

    k_prep_w<<<(128 * 256 + 5 * 128 * 128 + 255) / 256, 256, 0, stream>>>(W_lin, W1s, Wlt, Wt);

    // GCNConv (cast fused into GEMM)
    k_mgemm<D_IN><<<ggrid, 256, 0, stream>>>(x, Wlt, xwb, N_NODES);
    k_agg<0><<<agrid, 256, 0, stream>>>((const uint4*)xwb, nullptr, rp, cs, dinv, b_lin,
                                        nullptr, (uint4*)x0b, bns, N_NODES);

    // 5x GCN2Conv
    for (int i = 0; i < 5; ++i) {
        const unsigned short* zsrc = (i == 0) ? x0b : zb;
        if (i == 0)
            k_agg<1><<<agrid, 256, 0, stream>>>((const uint4*)zsrc, (const uint4*)x0b,
                                                rp, cs, nullptr, nullptr, nullptr,
                                                (uint4*)hb, bns, N_NODES);
        else
            k_agg<2><<<agrid, 256, 0, stream>>>((const uint4*)zsrc, (const uint4*)x0b,
                                                rp, cs, nullptr, nullptr, st,
                                                (uint4*)hb, bns, N_NODES);
        const unsigned short* W1 = Wt + (size_t)i * 128 * 128;
        if (i < 4) {
            k_lgemm<1><<<ggrid, 256, 0, stream>>>(hb, W1, zb, nullptr, bns, bns + 128, N_NODES);
            k_bn_fin<<<1, 128, 0, stream>>>(bns, bns + 128, gam + (size_t)i * 128,
                                            betp + (size_t)i * 128, st, N_NODES);
        } else {
            k_lgemm<2><<<ggrid, 256, 0, stream>>>(hb, W1, nullptr, out, nullptr, nullptr, N_NODES);
        }
    }
}